// Round 1
// baseline (193.751 us; speedup 1.0000x reference)
//
#include <hip/hip_runtime.h>
#include <hip/hip_bf16.h>

typedef unsigned int uint;
typedef unsigned short ushort;
typedef short bf16x8 __attribute__((ext_vector_type(8)));
typedef float f32x4 __attribute__((ext_vector_type(4)));

#define B_ 16
#define C_ 256
#define O_ 256
#define E_ 4
#define H_ 64
#define W_ 64
#define HW_ 4096
#define KK_ 2304   // C_*9

__device__ __forceinline__ ushort f2bf(float f) {
    uint u = __builtin_bit_cast(uint, f);
    uint r = (u + 0x7FFFu + ((u >> 16) & 1u)) >> 16;   // RNE
    return (ushort)r;
}

// ---------------- kernel 1: global average pool  ----------------
// grid = B_*C_ blocks, 256 threads. Each block reduces one [H,W] plane.
__global__ __launch_bounds__(256) void pool_kernel(const float* __restrict__ x,
                                                   float* __restrict__ pooled) {
    const int bc = blockIdx.x;
    const float4* p = (const float4*)(x + (size_t)bc * HW_);
    const int t = threadIdx.x;
    float s = 0.0f;
    #pragma unroll
    for (int j = 0; j < 4; ++j) {
        float4 v = p[t + j * 256];
        s += v.x + v.y + v.z + v.w;
    }
    #pragma unroll
    for (int off = 32; off > 0; off >>= 1) s += __shfl_down(s, off);
    __shared__ float red[4];
    if ((t & 63) == 0) red[t >> 6] = s;
    __syncthreads();
    if (t == 0) pooled[bc] = (red[0] + red[1] + red[2] + red[3]) * (1.0f / 4096.0f);
}

// ---------------- kernel 2: gating softmax ----------------
// 1 block, 64 threads: thread = b*4+e
__global__ __launch_bounds__(64) void gate_kernel(const float* __restrict__ pooled,
                                                  const float* __restrict__ gw,
                                                  float* __restrict__ gates) {
    const int t = threadIdx.x;
    const int b = t >> 2, e = t & 3;
    float logit = 0.0f;
    for (int c = 0; c < C_; ++c) logit += pooled[b * C_ + c] * gw[e * C_ + c];
    float m = logit;
    m = fmaxf(m, __shfl_xor(m, 1));
    m = fmaxf(m, __shfl_xor(m, 2));
    float ex = expf(logit - m);
    float sum = ex;
    sum += __shfl_xor(sum, 1);
    sum += __shfl_xor(sum, 2);
    gates[t] = ex / sum;
}

// ---------------- kernel 3: combine expert weights ----------------
// grid = O_ blocks, 256 threads. W_comb[b][o][k] bf16, k = c*9 + kh*3 + kw
__global__ __launch_bounds__(256) void combine_kernel(const float* __restrict__ We,
                                                      const float* __restrict__ gates,
                                                      ushort* __restrict__ Wc) {
    const int o = blockIdx.x;
    const int t = threadIdx.x;
    __shared__ float g[B_ * E_];
    if (t < B_ * E_) g[t] = gates[t];
    __syncthreads();
    const float* w0 = We + (size_t)o * KK_;
    #pragma unroll
    for (int j = 0; j < 9; ++j) {
        int i = t + j * 256;
        float w[4];
        #pragma unroll
        for (int e = 0; e < 4; ++e) w[e] = w0[(size_t)e * (O_ * KK_) + i];
        #pragma unroll
        for (int b = 0; b < B_; ++b) {
            float v = g[b*4+0]*w[0] + g[b*4+1]*w[1] + g[b*4+2]*w[2] + g[b*4+3]*w[3];
            Wc[((size_t)(b * O_ + o)) * KK_ + i] = f2bf(v);
        }
    }
}

// ---------------- kernel 4: implicit-GEMM conv via MFMA ----------------
// per sample: C[o][px] = sum_k Wc[o][k] * im2col[px][k],  k = c*9 + tap
// grid = (32 n-tiles, 2 o-tiles, 16 samples), 256 threads (4 waves)
__global__ __launch_bounds__(256) void conv_kernel(const float* __restrict__ x,
                                                   const ushort* __restrict__ Wc,
                                                   float* __restrict__ out) {
    __shared__ ushort As[128][40];   // [o][k] padded (80B rows -> ~2-way banks)
    __shared__ ushort Bs[128][40];   // [px][k] padded
    __shared__ uint ktab[KK_];       // per-k: rel offset (24b) | edge flags (4b)

    const int tid = threadIdx.x;
    const int b  = blockIdx.z;
    const int o0 = blockIdx.y * 128;
    const int n0 = blockIdx.x * 128;

    // build k -> (offset, edge-flag) table
    for (int k = tid; k < KK_; k += 256) {
        int c   = (k * 7282) >> 16;        // k/9 exact for k<3640
        int tap = k - 9 * c;
        int dh  = (tap * 11) >> 5;         // tap/3  (0..2 meaning -1..1)
        int dw  = tap - 3 * dh;
        int off = c * HW_ + (dh - 1) * W_ + (dw - 1) + 65;   // >= 0
        uint flg = (uint)((dh == 0) | ((dh == 2) << 1) | ((dw == 0) << 2) | ((dw == 2) << 3));
        ktab[k] = (uint)off | (flg << 24);
    }

    // B staging: thread handles 16 k's of one pixel
    const int px   = tid & 127;
    const int koff = (tid >> 7) << 4;          // 0 or 16
    const int n = n0 + px;
    const int h = n >> 6, w = n & 63;
    const uint bad = (uint)((h == 0) | ((h == 63) << 1) | ((w == 0) << 2) | ((w == 63) << 3));
    const float* xbase = x + (size_t)b * C_ * HW_ + n - 65;

    // A staging: thread handles 16 k's of one weight row
    const int arow  = tid >> 1;
    const int akoff = (tid & 1) << 4;          // 0 or 16
    const ushort* abase = Wc + ((size_t)(b * O_ + o0 + arow)) * KK_ + akoff;

    // fragment setup: wave -> 64x64 quadrant, 4x4 fragments of 16x16
    const int wid = tid >> 6, lane = tid & 63;
    const int lr = lane & 15, lg = lane >> 4;
    const int wro = (wid >> 1) * 64;
    const int wco = (wid & 1) * 64;

    f32x4 acc[4][4];
    #pragma unroll
    for (int i = 0; i < 4; ++i)
        #pragma unroll
        for (int j = 0; j < 4; ++j) acc[i][j] = (f32x4){0.f, 0.f, 0.f, 0.f};

    __syncthreads();   // ktab ready

    for (int step = 0; step < 72; ++step) {
        const int k0 = step * 32;

        // A tile: 16 bf16 contiguous (aligned 16B: 2304*2 and 32B offsets)
        uint4 av0 = *(const uint4*)(abase + k0);
        uint4 av1 = *(const uint4*)(abase + k0 + 8);

        // B tile: im2col gather, 16 scalars -> 8 packed dwords
        uint bw[8];
        #pragma unroll
        for (int jj = 0; jj < 8; ++jj) {
            uint e0 = ktab[k0 + koff + 2 * jj];
            uint e1 = ktab[k0 + koff + 2 * jj + 1];
            float v0 = ((e0 >> 24) & bad) ? 0.0f : xbase[e0 & 0x00FFFFFFu];
            float v1 = ((e1 >> 24) & bad) ? 0.0f : xbase[e1 & 0x00FFFFFFu];
            bw[jj] = (uint)f2bf(v0) | ((uint)f2bf(v1) << 16);
        }

        *(uint4*)&As[arow][akoff]     = av0;
        *(uint4*)&As[arow][akoff + 8] = av1;
        *(uint4*)&Bs[px][koff]     = make_uint4(bw[0], bw[1], bw[2], bw[3]);
        *(uint4*)&Bs[px][koff + 8] = make_uint4(bw[4], bw[5], bw[6], bw[7]);
        __syncthreads();

        bf16x8 aF[4], bF[4];
        #pragma unroll
        for (int m = 0; m < 4; ++m)
            aF[m] = *(const bf16x8*)&As[wro + m * 16 + lr][lg * 8];
        #pragma unroll
        for (int nn = 0; nn < 4; ++nn)
            bF[nn] = *(const bf16x8*)&Bs[wco + nn * 16 + lr][lg * 8];

        #pragma unroll
        for (int m = 0; m < 4; ++m)
            #pragma unroll
            for (int nn = 0; nn < 4; ++nn)
                acc[m][nn] = __builtin_amdgcn_mfma_f32_16x16x32_bf16(aF[m], bF[nn], acc[m][nn], 0, 0, 0);
        __syncthreads();
    }

    // epilogue: C/D layout col=lane&15, row=(lane>>4)*4+j  [m89-verified]
    #pragma unroll
    for (int m = 0; m < 4; ++m)
        #pragma unroll
        for (int nn = 0; nn < 4; ++nn)
            #pragma unroll
            for (int j = 0; j < 4; ++j) {
                int ro = o0 + wro + m * 16 + lg * 4 + j;
                int co = n0 + wco + nn * 16 + lr;
                out[((size_t)(b * O_ + ro)) * HW_ + co] = acc[m][nn][j];
            }
}

extern "C" void kernel_launch(void* const* d_in, const int* in_sizes, int n_in,
                              void* d_out, int out_size, void* d_ws, size_t ws_size,
                              hipStream_t stream) {
    const float* x  = (const float*)d_in[0];
    const float* We = (const float*)d_in[1];
    const float* gw = (const float*)d_in[2];
    float* out = (float*)d_out;

    float*  pooled = (float*)d_ws;                    // 16*256 floats
    float*  gates  = pooled + B_ * C_;                // 64 floats
    ushort* Wcomb  = (ushort*)((char*)d_ws + 32768);  // B*O*KK bf16 = 18.9 MB

    pool_kernel<<<B_ * C_, 256, 0, stream>>>(x, pooled);
    gate_kernel<<<1, 64, 0, stream>>>(pooled, gw, gates);
    combine_kernel<<<O_, 256, 0, stream>>>(We, gates, Wcomb);
    dim3 grid(HW_ / 128, O_ / 128, B_);
    conv_kernel<<<grid, 256, 0, stream>>>(x, Wcomb, out);
}

// Round 2
// 173.608 us; speedup vs baseline: 1.1160x; 1.1160x over previous
//
#include <hip/hip_runtime.h>
#include <hip/hip_bf16.h>

typedef unsigned int uint;
typedef unsigned short ushort;
typedef short bf16x8 __attribute__((ext_vector_type(8)));
typedef float f32x4 __attribute__((ext_vector_type(4)));

#define B_ 16
#define C_ 256
#define O_ 256
#define HW_ 4096
#define KK_ 2304   // 9 * 256, tap-major: k = tap*256 + c

__device__ __forceinline__ ushort f2bf(float f) {
    uint u = __builtin_bit_cast(uint, f);
    uint r = (u + 0x7FFFu + ((u >> 16) & 1u)) >> 16;   // RNE
    return (ushort)r;
}

// ---------------- kernel 1: NCHW f32 -> NHWC bf16 transpose + pooling partials --------
// grid (64 h, 16 b), 256 threads; thread = c. Per-lane sequential reads (L1/L2 absorb
// the cross-lane stride), writes coalesced 512B per w-plane. Also emits row sums.
__global__ __launch_bounds__(256) void transpose_kernel(const float* __restrict__ x,
                                                        ushort* __restrict__ xT,
                                                        float* __restrict__ part) {
    const int h = blockIdx.x, b = blockIdx.y;
    const int c = threadIdx.x;
    const float* src = x + (((size_t)(b * C_ + c)) * 64 + h) * 64;   // x[b][c][h][0..63]
    ushort* dst = xT + ((size_t)(b * HW_) + h * 64) * C_ + c;        // xT[b][h][w][c]
    float s = 0.0f;
    #pragma unroll
    for (int j = 0; j < 16; ++j) {
        float4 v = ((const float4*)src)[j];
        s += v.x + v.y + v.z + v.w;
        dst[(j * 4 + 0) * C_] = f2bf(v.x);
        dst[(j * 4 + 1) * C_] = f2bf(v.y);
        dst[(j * 4 + 2) * C_] = f2bf(v.z);
        dst[(j * 4 + 3) * C_] = f2bf(v.w);
    }
    part[(b * C_ + c) * 64 + h] = s;   // coalesced across lanes
}

// ---------------- kernel 2: pooled reduce + gating softmax ----------------
// grid 16 (=b), 256 threads; thread = c
__global__ __launch_bounds__(256) void gate_kernel(const float* __restrict__ part,
                                                   const float* __restrict__ gw,
                                                   float* __restrict__ gates) {
    const int b = blockIdx.x, c = threadIdx.x;
    const float4* pp = (const float4*)(part + (size_t)(b * C_ + c) * 64);
    float p = 0.0f;
    #pragma unroll
    for (int j = 0; j < 16; ++j) { float4 v = pp[j]; p += v.x + v.y + v.z + v.w; }
    p *= (1.0f / 4096.0f);
    float l0 = p * gw[0 * C_ + c], l1 = p * gw[1 * C_ + c];
    float l2 = p * gw[2 * C_ + c], l3 = p * gw[3 * C_ + c];
    #pragma unroll
    for (int off = 32; off; off >>= 1) {
        l0 += __shfl_down(l0, off); l1 += __shfl_down(l1, off);
        l2 += __shfl_down(l2, off); l3 += __shfl_down(l3, off);
    }
    __shared__ float red[4][4];
    const int wid = c >> 6, lane = c & 63;
    if (lane == 0) { red[wid][0] = l0; red[wid][1] = l1; red[wid][2] = l2; red[wid][3] = l3; }
    __syncthreads();
    if (c < 4) {
        float logit = red[0][c] + red[1][c] + red[2][c] + red[3][c];
        float m = logit;
        m = fmaxf(m, __shfl_xor(m, 1)); m = fmaxf(m, __shfl_xor(m, 2));
        float ex = expf(logit - m);
        float ssum = ex; ssum += __shfl_xor(ssum, 1); ssum += __shfl_xor(ssum, 2);
        gates[b * 4 + c] = ex / ssum;
    }
}

// ---------------- kernel 3: combine expert weights (tap-major k) ----------------
// grid 256 (=o), 256 threads; thread = c. Wc[b][o][tap*256+c] bf16.
__global__ __launch_bounds__(256) void combine_kernel(const float* __restrict__ We,
                                                      const float* __restrict__ gates,
                                                      ushort* __restrict__ Wc) {
    const int o = blockIdx.x, c = threadIdx.x;
    __shared__ float g[64];
    if (c < 64) g[c] = gates[c];
    __syncthreads();
    float w[4][9];
    #pragma unroll
    for (int e = 0; e < 4; ++e) {
        const float* p = We + (((size_t)e * O_ + o) * C_ + c) * 9;
        #pragma unroll
        for (int tap = 0; tap < 9; ++tap) w[e][tap] = p[tap];
    }
    #pragma unroll
    for (int b = 0; b < B_; ++b) {
        float g0 = g[b*4+0], g1 = g[b*4+1], g2 = g[b*4+2], g3 = g[b*4+3];
        #pragma unroll
        for (int tap = 0; tap < 9; ++tap) {
            float v = g0*w[0][tap] + g1*w[1][tap] + g2*w[2][tap] + g3*w[3][tap];
            Wc[((size_t)(b * O_ + o)) * KK_ + tap * C_ + c] = f2bf(v);  // coalesced
        }
    }
}

// ---------------- kernel 4: implicit-GEMM conv via MFMA (tap-major K) ----------------
// grid = (32 n-tiles, 2 o-tiles, 16 samples), 256 threads (4 waves)
// K-step = 32 = one c-chunk of one tap; B staging is pure vector loads from NHWC bf16.
__global__ __launch_bounds__(256) void conv_kernel(const ushort* __restrict__ xT,
                                                   const ushort* __restrict__ Wc,
                                                   float* __restrict__ out) {
    __shared__ ushort As[128][40];   // [o][k] pad -> 80B rows (16B aligned)
    __shared__ ushort Bs[128][40];   // [px][k]

    const int tid = threadIdx.x;
    const int b  = blockIdx.z;
    const int o0 = blockIdx.y * 128;
    const int n0 = blockIdx.x * 128;

    // staging roles: thread = (row, half); row is both A-row and B-pixel
    const int row  = tid >> 1;          // 0..127
    const int half = tid & 1;           // k-offset 0/16
    const int n = n0 + row, h = n >> 6, w = n & 63;
    const ushort* xb    = xT + (size_t)b * HW_ * C_;
    const ushort* abase = Wc + ((size_t)(b * O_ + o0 + row)) * KK_ + half * 16;

    // fragment setup: wave -> 64x64 quadrant, 4x4 fragments of 16x16
    const int wid = tid >> 6, lane = tid & 63;
    const int lr = lane & 15, lg = lane >> 4;
    const int wro = (wid >> 1) * 64;
    const int wco = (wid & 1) * 64;

    f32x4 acc[4][4];
    #pragma unroll
    for (int i = 0; i < 4; ++i)
        #pragma unroll
        for (int j = 0; j < 4; ++j) acc[i][j] = (f32x4){0.f, 0.f, 0.f, 0.f};

    for (int step = 0; step < 72; ++step) {
        const int tap = step >> 3;              // uniform per step
        const int c0  = (step & 7) << 5;
        const int t3  = (tap * 11) >> 5;        // tap/3
        const int dh  = t3 - 1;
        const int dw  = (tap - 3 * t3) - 1;
        const int hh = h + dh, ww = w + dw;
        const bool ok = ((uint)hh < 64u) && ((uint)ww < 64u);

        uint4 b0 = make_uint4(0,0,0,0), b1 = make_uint4(0,0,0,0);
        if (ok) {
            const ushort* src = xb + (size_t)(hh * 64 + ww) * C_ + c0 + half * 16;
            b0 = *(const uint4*)(src);
            b1 = *(const uint4*)(src + 8);
        }
        uint4 a0 = *(const uint4*)(abase + step * 32);
        uint4 a1 = *(const uint4*)(abase + step * 32 + 8);

        *(uint4*)&As[row][half * 16]     = a0;
        *(uint4*)&As[row][half * 16 + 8] = a1;
        *(uint4*)&Bs[row][half * 16]     = b0;
        *(uint4*)&Bs[row][half * 16 + 8] = b1;
        __syncthreads();

        bf16x8 aF[4], bF[4];
        #pragma unroll
        for (int m = 0; m < 4; ++m)
            aF[m] = *(const bf16x8*)&As[wro + m * 16 + lr][lg * 8];
        #pragma unroll
        for (int nn = 0; nn < 4; ++nn)
            bF[nn] = *(const bf16x8*)&Bs[wco + nn * 16 + lr][lg * 8];

        #pragma unroll
        for (int m = 0; m < 4; ++m)
            #pragma unroll
            for (int nn = 0; nn < 4; ++nn)
                acc[m][nn] = __builtin_amdgcn_mfma_f32_16x16x32_bf16(aF[m], bF[nn], acc[m][nn], 0, 0, 0);
        __syncthreads();
    }

    // epilogue: C/D layout col=lane&15, row=(lane>>4)*4+j
    #pragma unroll
    for (int m = 0; m < 4; ++m)
        #pragma unroll
        for (int nn = 0; nn < 4; ++nn)
            #pragma unroll
            for (int j = 0; j < 4; ++j) {
                int ro = o0 + wro + m * 16 + lg * 4 + j;
                int co = n0 + wco + nn * 16 + lr;
                out[((size_t)(b * O_ + ro)) * HW_ + co] = acc[m][nn][j];
            }
}

extern "C" void kernel_launch(void* const* d_in, const int* in_sizes, int n_in,
                              void* d_out, int out_size, void* d_ws, size_t ws_size,
                              hipStream_t stream) {
    const float* x  = (const float*)d_in[0];
    const float* We = (const float*)d_in[1];
    const float* gw = (const float*)d_in[2];
    float* out = (float*)d_out;

    // ws layout: part @0 (256 KB), gates @262144, Wc @263168 (18.87 MB, ends 19137536),
    //            xT @19137536 (33.55 MB) -> total ~52.7 MB
    float*  part  = (float*)d_ws;
    float*  gates = (float*)((char*)d_ws + 262144);
    ushort* Wcomb = (ushort*)((char*)d_ws + 263168);
    ushort* xTp   = (ushort*)((char*)d_ws + 19137536);

    transpose_kernel<<<dim3(64, 16), 256, 0, stream>>>(x, xTp, part);
    gate_kernel<<<16, 256, 0, stream>>>(part, gw, gates);
    combine_kernel<<<O_, 256, 0, stream>>>(We, gates, Wcomb);
    dim3 grid(HW_ / 128, O_ / 128, B_);
    conv_kernel<<<grid, 256, 0, stream>>>(xTp, Wcomb, out);
}

// Round 3
// 154.313 us; speedup vs baseline: 1.2556x; 1.1250x over previous
//
#include <hip/hip_runtime.h>
#include <hip/hip_bf16.h>

typedef unsigned int uint;
typedef unsigned short ushort;
typedef short bf16x8 __attribute__((ext_vector_type(8)));
typedef float f32x4 __attribute__((ext_vector_type(4)));

#define B_ 16
#define C_ 256
#define O_ 256
#define HW_ 4096
#define KK_ 2304   // 9 * 256, tap-major: k = tap*256 + c
#define HP_ 66     // halo-padded spatial dim

__device__ __forceinline__ ushort f2bf(float f) {
    uint u = __builtin_bit_cast(uint, f);
    uint r = (u + 0x7FFFu + ((u >> 16) & 1u)) >> 16;   // RNE
    return (ushort)r;
}

// async global->LDS, 16B per lane; LDS dest is wave-uniform base + lane*16
__device__ __forceinline__ void gl16(const ushort* g, ushort* l) {
    __builtin_amdgcn_global_load_lds(
        (const __attribute__((address_space(1))) void*)g,
        (__attribute__((address_space(3))) void*)l,
        16, 0, 0);
}

// ---------------- kernel 1: NCHW f32 -> padded NHWC bf16 + pooling partials ----------
// grid (64 h, 16 b), 256 threads; thread = c.
__global__ __launch_bounds__(256) void transpose_kernel(const float* __restrict__ x,
                                                        ushort* __restrict__ xT,
                                                        float* __restrict__ part) {
    const int h = blockIdx.x, b = blockIdx.y;
    const int c = threadIdx.x;
    const float* src = x + (((size_t)(b * C_ + c)) * 64 + h) * 64;        // x[b][c][h][*]
    ushort* dst = xT + (((size_t)(b * HP_) + h + 1) * HP_ + 1) * C_ + c;  // xT[b][h+1][1][c]
    float s = 0.0f;
    #pragma unroll
    for (int j = 0; j < 16; ++j) {
        float4 v = ((const float4*)src)[j];
        s += v.x + v.y + v.z + v.w;
        dst[(j * 4 + 0) * C_] = f2bf(v.x);
        dst[(j * 4 + 1) * C_] = f2bf(v.y);
        dst[(j * 4 + 2) * C_] = f2bf(v.z);
        dst[(j * 4 + 3) * C_] = f2bf(v.w);
    }
    part[(b * C_ + c) * 64 + h] = s;
}

// ---------------- kernel 1b: zero the spatial halo of xT ----------------
// grid (16 b, 13), 256 threads; 260 halo pixels per sample, 20 per block.y
__global__ __launch_bounds__(256) void halo_kernel(ushort* __restrict__ xT) {
    const int b = blockIdx.x, q = blockIdx.y, c = threadIdx.x;
    #pragma unroll
    for (int t = 0; t < 20; ++t) {
        int i = q * 20 + t;
        if (i >= 260) break;
        int hp, wp;
        if (i < 66)       { hp = 0;       wp = i;       }
        else if (i < 132) { hp = 65;      wp = i - 66;  }
        else if (i < 196) { hp = i - 131; wp = 0;       }
        else              { hp = i - 195; wp = 65;      }
        xT[(((size_t)b * HP_ + hp) * HP_ + wp) * C_ + c] = 0;
    }
}

// ---------------- kernel 2: pooled reduce + gating softmax ----------------
__global__ __launch_bounds__(256) void gate_kernel(const float* __restrict__ part,
                                                   const float* __restrict__ gw,
                                                   float* __restrict__ gates) {
    const int b = blockIdx.x, c = threadIdx.x;
    const float4* pp = (const float4*)(part + (size_t)(b * C_ + c) * 64);
    float p = 0.0f;
    #pragma unroll
    for (int j = 0; j < 16; ++j) { float4 v = pp[j]; p += v.x + v.y + v.z + v.w; }
    p *= (1.0f / 4096.0f);
    float l0 = p * gw[0 * C_ + c], l1 = p * gw[1 * C_ + c];
    float l2 = p * gw[2 * C_ + c], l3 = p * gw[3 * C_ + c];
    #pragma unroll
    for (int off = 32; off; off >>= 1) {
        l0 += __shfl_down(l0, off); l1 += __shfl_down(l1, off);
        l2 += __shfl_down(l2, off); l3 += __shfl_down(l3, off);
    }
    __shared__ float red[4][4];
    const int wid = c >> 6, lane = c & 63;
    if (lane == 0) { red[wid][0] = l0; red[wid][1] = l1; red[wid][2] = l2; red[wid][3] = l3; }
    __syncthreads();
    if (c < 4) {
        float logit = red[0][c] + red[1][c] + red[2][c] + red[3][c];
        float m = logit;
        m = fmaxf(m, __shfl_xor(m, 1)); m = fmaxf(m, __shfl_xor(m, 2));
        float ex = expf(logit - m);
        float ssum = ex; ssum += __shfl_xor(ssum, 1); ssum += __shfl_xor(ssum, 2);
        gates[b * 4 + c] = ex / ssum;
    }
}

// ---------------- kernel 3: combine expert weights (tap-major k) ----------------
__global__ __launch_bounds__(256) void combine_kernel(const float* __restrict__ We,
                                                      const float* __restrict__ gates,
                                                      ushort* __restrict__ Wc) {
    const int o = blockIdx.x, c = threadIdx.x;
    __shared__ float g[64];
    if (c < 64) g[c] = gates[c];
    __syncthreads();
    float w[4][9];
    #pragma unroll
    for (int e = 0; e < 4; ++e) {
        const float* p = We + (((size_t)e * O_ + o) * C_ + c) * 9;
        #pragma unroll
        for (int tap = 0; tap < 9; ++tap) w[e][tap] = p[tap];
    }
    #pragma unroll
    for (int b = 0; b < B_; ++b) {
        float g0 = g[b*4+0], g1 = g[b*4+1], g2 = g[b*4+2], g3 = g[b*4+3];
        #pragma unroll
        for (int tap = 0; tap < 9; ++tap) {
            float v = g0*w[0][tap] + g1*w[1][tap] + g2*w[2][tap] + g3*w[3][tap];
            Wc[((size_t)(b * O_ + o)) * KK_ + tap * C_ + c] = f2bf(v);
        }
    }
}

// ---------------- kernel 4: implicit-GEMM conv, async-DMA double-buffered -------------
// grid = (32 n-tiles, 2 o-tiles, 16 samples), 256 threads (4 waves)
__global__ __launch_bounds__(256) void conv_kernel(const ushort* __restrict__ xT,
                                                   const ushort* __restrict__ Wc,
                                                   float* __restrict__ out) {
    __shared__ ushort As[2][128][32];   // [buf][o][k]  linear 64B rows (DMA dest)
    __shared__ ushort Bs[2][128][32];   // [buf][px][k]

    const int tid = threadIdx.x;
    const int b  = blockIdx.z;
    const int o0 = blockIdx.y * 128;
    const int n0 = blockIdx.x * 128;
    const int wid = tid >> 6, lane = tid & 63;
    const int lr = lane & 15, lg = lane >> 4;
    const int wro = (wid >> 1) * 64;
    const int wco = (wid & 1) * 64;

    // staging lane roles: each wave DMAs 2x1KB of A and 2x1KB of B per step
    const int srow = lane >> 2;            // 0..15 row within 16-row chunk
    const int scol = (lane & 3) * 8;       // channel offset within 32
    const ushort* aptr = Wc + ((size_t)(b * O_ + o0 + 32 * wid + srow)) * KK_ + scol;
    const ushort* xb = xT + (size_t)b * HP_ * HP_ * C_;
    const int pix0 = n0 + 32 * wid + srow;
    const int pix1 = pix0 + 16;
    const ushort* bptr0 = xb + ((size_t)(((pix0 >> 6) + 1) * HP_ + (pix0 & 63) + 1)) * C_ + scol;
    const ushort* bptr1 = xb + ((size_t)(((pix1 >> 6) + 1) * HP_ + (pix1 & 63) + 1)) * C_ + scol;

    f32x4 acc[4][4];
    #pragma unroll
    for (int i = 0; i < 4; ++i)
        #pragma unroll
        for (int j = 0; j < 4; ++j) acc[i][j] = (f32x4){0.f, 0.f, 0.f, 0.f};

    auto stage = [&](int buf, int step) {
        const int tap = step >> 3;
        const int t3  = (tap * 11) >> 5;               // tap/3
        const int toff = ((t3 - 1) * HP_ + (tap - 3 * t3 - 1)) * C_ + (step & 7) * 32;
        const int k0 = step * 32;
        gl16(aptr + k0,                     &As[buf][32 * wid][0]);
        gl16(aptr + (size_t)16 * KK_ + k0,  &As[buf][32 * wid + 16][0]);
        gl16(bptr0 + toff,                  &Bs[buf][32 * wid][0]);
        gl16(bptr1 + toff,                  &Bs[buf][32 * wid + 16][0]);
    };

    stage(0, 0);
    __syncthreads();   // drains vmcnt(0): buf0 ready

    int cur = 0;
    for (int step = 0; step < 71; ++step) {
        stage(cur ^ 1, step + 1);          // DMA next K-step while computing this one
        bf16x8 aF[4], bF[4];
        #pragma unroll
        for (int m = 0; m < 4; ++m)
            aF[m] = *(const bf16x8*)&As[cur][wro + m * 16 + lr][lg * 8];
        #pragma unroll
        for (int nn = 0; nn < 4; ++nn)
            bF[nn] = *(const bf16x8*)&Bs[cur][wco + nn * 16 + lr][lg * 8];
        #pragma unroll
        for (int m = 0; m < 4; ++m)
            #pragma unroll
            for (int nn = 0; nn < 4; ++nn)
                acc[m][nn] = __builtin_amdgcn_mfma_f32_16x16x32_bf16(aF[m], bF[nn], acc[m][nn], 0, 0, 0);
        __syncthreads();                   // vmcnt(0)+barrier: next buf ready, cur consumed
        cur ^= 1;
    }
    {   // last K-step, no prefetch
        bf16x8 aF[4], bF[4];
        #pragma unroll
        for (int m = 0; m < 4; ++m)
            aF[m] = *(const bf16x8*)&As[cur][wro + m * 16 + lr][lg * 8];
        #pragma unroll
        for (int nn = 0; nn < 4; ++nn)
            bF[nn] = *(const bf16x8*)&Bs[cur][wco + nn * 16 + lr][lg * 8];
        #pragma unroll
        for (int m = 0; m < 4; ++m)
            #pragma unroll
            for (int nn = 0; nn < 4; ++nn)
                acc[m][nn] = __builtin_amdgcn_mfma_f32_16x16x32_bf16(aF[m], bF[nn], acc[m][nn], 0, 0, 0);
    }

    // epilogue: C/D layout col=lane&15, row=(lane>>4)*4+j
    #pragma unroll
    for (int m = 0; m < 4; ++m)
        #pragma unroll
        for (int nn = 0; nn < 4; ++nn)
            #pragma unroll
            for (int j = 0; j < 4; ++j) {
                int ro = o0 + wro + m * 16 + lg * 4 + j;
                int co = n0 + wco + nn * 16 + lr;
                out[((size_t)(b * O_ + ro)) * HW_ + co] = acc[m][nn][j];
            }
}

extern "C" void kernel_launch(void* const* d_in, const int* in_sizes, int n_in,
                              void* d_out, int out_size, void* d_ws, size_t ws_size,
                              hipStream_t stream) {
    const float* x  = (const float*)d_in[0];
    const float* We = (const float*)d_in[1];
    const float* gw = (const float*)d_in[2];
    float* out = (float*)d_out;

    // ws: part @0 (256KB), gates @262144, Wc @263168 (18.87MB -> 19137536),
    //     xT @19137536 (16*66*66*256*2B = 35.68MB -> ~54.8MB total)
    float*  part  = (float*)d_ws;
    float*  gates = (float*)((char*)d_ws + 262144);
    ushort* Wcomb = (ushort*)((char*)d_ws + 263168);
    ushort* xTp   = (ushort*)((char*)d_ws + 19137536);

    transpose_kernel<<<dim3(64, 16), 256, 0, stream>>>(x, xTp, part);
    halo_kernel<<<dim3(16, 13), 256, 0, stream>>>(xTp);
    gate_kernel<<<16, 256, 0, stream>>>(part, gw, gates);
    combine_kernel<<<O_, 256, 0, stream>>>(We, gates, Wcomb);
    dim3 grid(HW_ / 128, O_ / 128, B_);
    conv_kernel<<<grid, 256, 0, stream>>>(xTp, Wcomb, out);
}

// Round 4
// 152.086 us; speedup vs baseline: 1.2740x; 1.0146x over previous
//
#include <hip/hip_runtime.h>
#include <hip/hip_bf16.h>

typedef unsigned int uint;
typedef unsigned short ushort;
typedef short bf16x8 __attribute__((ext_vector_type(8)));
typedef ushort u16x8 __attribute__((ext_vector_type(8)));
typedef float f32x4 __attribute__((ext_vector_type(4)));

#define B_ 16
#define C_ 256
#define O_ 256
#define HW_ 4096
#define KK_ 2304   // 9 * 256, tap-major: k = tap*256 + c
#define HP_ 66     // halo-padded spatial dim

__device__ __forceinline__ ushort f2bf(float f) {
    uint u = __builtin_bit_cast(uint, f);
    uint r = (u + 0x7FFFu + ((u >> 16) & 1u)) >> 16;   // RNE
    return (ushort)r;
}

// async global->LDS, 16B per lane; LDS dest is wave-uniform base + lane*16
__device__ __forceinline__ void gl16(const ushort* g, ushort* l) {
    __builtin_amdgcn_global_load_lds(
        (const __attribute__((address_space(1))) void*)g,
        (__attribute__((address_space(3))) void*)l,
        16, 0, 0);
}

// ---------------- kernel 1: NCHW f32 -> padded NHWC bf16 + pooling partials ----------
// grid (64 h, 16 b), 256 threads; thread = c on load side. LDS-staged transpose so
// global writes are ushort8-vectorized (was 64 scalar 2B stores/thread).
__global__ __launch_bounds__(256) void transpose_kernel(const float* __restrict__ x,
                                                        ushort* __restrict__ xT,
                                                        float* __restrict__ part) {
    __shared__ ushort tl[64][264];   // [w][c], pad 8 -> row stride 528B
    const int h = blockIdx.x, b = blockIdx.y;
    const int c = threadIdx.x;
    const float* src = x + (((size_t)(b * C_ + c)) * 64 + h) * 64;   // x[b][c][h][*]
    float s = 0.0f;
    #pragma unroll
    for (int j = 0; j < 16; ++j) {
        float4 v = ((const float4*)src)[j];
        s += v.x + v.y + v.z + v.w;
        tl[j * 4 + 0][c] = f2bf(v.x);
        tl[j * 4 + 1][c] = f2bf(v.y);
        tl[j * 4 + 2][c] = f2bf(v.z);
        tl[j * 4 + 3][c] = f2bf(v.w);
    }
    part[(b * C_ + c) * 64 + h] = s;
    __syncthreads();
    const int cw = threadIdx.x & 31, rw = threadIdx.x >> 5;
    ushort* dstrow = xT + (((size_t)(b * HP_) + h + 1) * HP_ + 1) * C_;  // xT[b][h+1][1][0]
    #pragma unroll
    for (int j = 0; j < 8; ++j) {
        int w = rw + 8 * j;
        *(u16x8*)(dstrow + (size_t)w * C_ + cw * 8) = *(const u16x8*)&tl[w][cw * 8];
    }
}

// ---------------- kernel 1b: zero the spatial halo of xT ----------------
__global__ __launch_bounds__(256) void halo_kernel(ushort* __restrict__ xT) {
    const int b = blockIdx.x, q = blockIdx.y, c = threadIdx.x;
    #pragma unroll
    for (int t = 0; t < 20; ++t) {
        int i = q * 20 + t;
        if (i >= 260) break;
        int hp, wp;
        if (i < 66)       { hp = 0;       wp = i;       }
        else if (i < 132) { hp = 65;      wp = i - 66;  }
        else if (i < 196) { hp = i - 131; wp = 0;       }
        else              { hp = i - 195; wp = 65;      }
        xT[(((size_t)b * HP_ + hp) * HP_ + wp) * C_ + c] = 0;
    }
}

// ---------------- kernel 2: pooled reduce + gating softmax ----------------
__global__ __launch_bounds__(256) void gate_kernel(const float* __restrict__ part,
                                                   const float* __restrict__ gw,
                                                   float* __restrict__ gates) {
    const int b = blockIdx.x, c = threadIdx.x;
    const float4* pp = (const float4*)(part + (size_t)(b * C_ + c) * 64);
    float p = 0.0f;
    #pragma unroll
    for (int j = 0; j < 16; ++j) { float4 v = pp[j]; p += v.x + v.y + v.z + v.w; }
    p *= (1.0f / 4096.0f);
    float l0 = p * gw[0 * C_ + c], l1 = p * gw[1 * C_ + c];
    float l2 = p * gw[2 * C_ + c], l3 = p * gw[3 * C_ + c];
    #pragma unroll
    for (int off = 32; off; off >>= 1) {
        l0 += __shfl_down(l0, off); l1 += __shfl_down(l1, off);
        l2 += __shfl_down(l2, off); l3 += __shfl_down(l3, off);
    }
    __shared__ float red[4][4];
    const int wid = c >> 6, lane = c & 63;
    if (lane == 0) { red[wid][0] = l0; red[wid][1] = l1; red[wid][2] = l2; red[wid][3] = l3; }
    __syncthreads();
    if (c < 4) {
        float logit = red[0][c] + red[1][c] + red[2][c] + red[3][c];
        float m = logit;
        m = fmaxf(m, __shfl_xor(m, 1)); m = fmaxf(m, __shfl_xor(m, 2));
        float ex = expf(logit - m);
        float ssum = ex; ssum += __shfl_xor(ssum, 1); ssum += __shfl_xor(ssum, 2);
        gates[b * 4 + c] = ex / ssum;
    }
}

// ---------------- kernel 3: combine expert weights (tap-major k) ----------------
__global__ __launch_bounds__(256) void combine_kernel(const float* __restrict__ We,
                                                      const float* __restrict__ gates,
                                                      ushort* __restrict__ Wc) {
    const int o = blockIdx.x, c = threadIdx.x;
    __shared__ float g[64];
    if (c < 64) g[c] = gates[c];
    __syncthreads();
    float w[4][9];
    #pragma unroll
    for (int e = 0; e < 4; ++e) {
        const float* p = We + (((size_t)e * O_ + o) * C_ + c) * 9;
        #pragma unroll
        for (int tap = 0; tap < 9; ++tap) w[e][tap] = p[tap];
    }
    #pragma unroll
    for (int b = 0; b < B_; ++b) {
        float g0 = g[b*4+0], g1 = g[b*4+1], g2 = g[b*4+2], g3 = g[b*4+3];
        #pragma unroll
        for (int tap = 0; tap < 9; ++tap) {
            float v = g0*w[0][tap] + g1*w[1][tap] + g2*w[2][tap] + g3*w[3][tap];
            Wc[((size_t)(b * O_ + o)) * KK_ + tap * C_ + c] = f2bf(v);
        }
    }
}

// ---------------- kernel 4: implicit-GEMM conv, 3-slot ring + counted vmcnt ----------
// grid = (32 n-tiles, 2 o-tiles, 16 samples), 256 threads (4 waves).
// Slot ring: compute step t from slot t%3 while step t+2 DMAs into slot (t+2)%3.
// Counted s_waitcnt vmcnt(4) (= "t landed, t+1 in flight") — never vmcnt(0) mid-loop.
// LDS source-side XOR swizzle (granule ^= (row>>1)&3) makes fragment ds_read_b128
// exactly 2 lanes/bank (free); DMA dest stays linear per the gload_lds rule.
__global__ __launch_bounds__(256, 3) void conv_kernel(const ushort* __restrict__ xT,
                                                      const ushort* __restrict__ Wc,
                                                      float* __restrict__ out) {
    __shared__ ushort As[3][128][32];   // [slot][o][k]  64B rows, linear DMA dest
    __shared__ ushort Bs[3][128][32];   // [slot][px][k]

    const int tid = threadIdx.x;
    const int b  = blockIdx.z;
    const int o0 = blockIdx.y * 128;
    const int n0 = blockIdx.x * 128;
    const int wid = tid >> 6, lane = tid & 63;
    const int lr = lane & 15, lg = lane >> 4;
    const int wro = (wid >> 1) * 64;
    const int wco = (wid & 1) * 64;
    const int swz = (lg ^ ((lr >> 1) & 3)) * 8;     // read-side swizzled column (elems)

    // staging lane roles: 16 rows x 64B per gl16; source granule pre-swizzled
    const int srow = lane >> 2;                      // 0..15
    const int scol = ((lane & 3) ^ ((lane >> 3) & 3)) * 8;
    const ushort* aptr = Wc + ((size_t)(b * O_ + o0 + 32 * wid + srow)) * KK_ + scol;
    const ushort* xb = xT + (size_t)b * HP_ * HP_ * C_;
    const int pix0 = n0 + 32 * wid + srow;
    const int pix1 = pix0 + 16;
    const ushort* bptr0 = xb + ((size_t)(((pix0 >> 6) + 1) * HP_ + (pix0 & 63) + 1)) * C_ + scol;
    const ushort* bptr1 = xb + ((size_t)(((pix1 >> 6) + 1) * HP_ + (pix1 & 63) + 1)) * C_ + scol;

    f32x4 acc[4][4];
    #pragma unroll
    for (int i = 0; i < 4; ++i)
        #pragma unroll
        for (int j = 0; j < 4; ++j) acc[i][j] = (f32x4){0.f, 0.f, 0.f, 0.f};

    auto stage = [&](int buf, int step) {
        const int tap = step >> 3;
        const int t3  = (tap * 11) >> 5;             // tap/3
        const int toff = ((t3 - 1) * HP_ + (tap - 3 * t3 - 1)) * C_ + (step & 7) * 32;
        const int k0 = step * 32;
        gl16(aptr + k0,                    &As[buf][32 * wid][0]);
        gl16(aptr + (size_t)16 * KK_ + k0, &As[buf][32 * wid + 16][0]);
        gl16(bptr0 + toff,                 &Bs[buf][32 * wid][0]);
        gl16(bptr1 + toff,                 &Bs[buf][32 * wid + 16][0]);
    };

    auto compute = [&](int buf) {
        bf16x8 aF[4], bF[4];
        #pragma unroll
        for (int m = 0; m < 4; ++m)
            aF[m] = *(const bf16x8*)&As[buf][wro + m * 16 + lr][swz];
        #pragma unroll
        for (int nn = 0; nn < 4; ++nn)
            bF[nn] = *(const bf16x8*)&Bs[buf][wco + nn * 16 + lr][swz];
        #pragma unroll
        for (int m = 0; m < 4; ++m)
            #pragma unroll
            for (int nn = 0; nn < 4; ++nn)
                acc[m][nn] = __builtin_amdgcn_mfma_f32_16x16x32_bf16(aF[m], bF[nn], acc[m][nn], 0, 0, 0);
    };

    stage(0, 0);
    stage(1, 1);

    #pragma unroll 1
    for (int t = 0; t < 69; t += 3) {
        asm volatile("s_waitcnt vmcnt(4)" ::: "memory");
        __builtin_amdgcn_s_barrier();
        stage(2, t + 2);
        compute(0);
        asm volatile("s_waitcnt vmcnt(4)" ::: "memory");
        __builtin_amdgcn_s_barrier();
        stage(0, t + 3);
        compute(1);
        asm volatile("s_waitcnt vmcnt(4)" ::: "memory");
        __builtin_amdgcn_s_barrier();
        stage(1, t + 4);
        compute(2);
    }
    // tail: steps 69, 70, 71 (stage of 71 issued at t=69; then drain)
    asm volatile("s_waitcnt vmcnt(4)" ::: "memory");
    __builtin_amdgcn_s_barrier();
    stage(2, 71);
    compute(0);
    asm volatile("s_waitcnt vmcnt(4)" ::: "memory");
    __builtin_amdgcn_s_barrier();
    compute(1);
    asm volatile("s_waitcnt vmcnt(0)" ::: "memory");
    __builtin_amdgcn_s_barrier();
    compute(2);

    // epilogue: C/D layout col=lane&15, row=(lane>>4)*4+j
    #pragma unroll
    for (int m = 0; m < 4; ++m)
        #pragma unroll
        for (int nn = 0; nn < 4; ++nn)
            #pragma unroll
            for (int j = 0; j < 4; ++j) {
                int ro = o0 + wro + m * 16 + lg * 4 + j;
                int co = n0 + wco + nn * 16 + lr;
                out[((size_t)(b * O_ + ro)) * HW_ + co] = acc[m][nn][j];
            }
}

extern "C" void kernel_launch(void* const* d_in, const int* in_sizes, int n_in,
                              void* d_out, int out_size, void* d_ws, size_t ws_size,
                              hipStream_t stream) {
    const float* x  = (const float*)d_in[0];
    const float* We = (const float*)d_in[1];
    const float* gw = (const float*)d_in[2];
    float* out = (float*)d_out;

    // ws: part @0 (256KB), gates @262144, Wc @263168 (18.87MB -> 19137536),
    //     xT @19137536 (16*66*66*256*2B = 35.68MB -> ~54.8MB total)
    float*  part  = (float*)d_ws;
    float*  gates = (float*)((char*)d_ws + 262144);
    ushort* Wcomb = (ushort*)((char*)d_ws + 263168);
    ushort* xTp   = (ushort*)((char*)d_ws + 19137536);

    transpose_kernel<<<dim3(64, 16), 256, 0, stream>>>(x, xTp, part);
    halo_kernel<<<dim3(16, 13), 256, 0, stream>>>(xTp);
    gate_kernel<<<16, 256, 0, stream>>>(part, gw, gates);
    combine_kernel<<<O_, 256, 0, stream>>>(We, gates, Wcomb);
    dim3 grid(HW_ / 128, O_ / 128, B_);
    conv_kernel<<<grid, 256, 0, stream>>>(xTp, Wcomb, out);
}

// Round 5
// 125.430 us; speedup vs baseline: 1.5447x; 1.2125x over previous
//
#include <hip/hip_runtime.h>
#include <hip/hip_bf16.h>

typedef unsigned int uint;
typedef unsigned short ushort;
typedef short bf16x8 __attribute__((ext_vector_type(8)));
typedef ushort u16x8 __attribute__((ext_vector_type(8)));
typedef float f32x4 __attribute__((ext_vector_type(4)));

#define B_ 16
#define C_ 256
#define O_ 256
#define HW_ 4096
#define KK_ 2304   // 9 * 256, tap-major: k = tap*256 + c
#define HP_ 66     // halo-padded spatial dim

__device__ __forceinline__ ushort f2bf(float f) {
    uint u = __builtin_bit_cast(uint, f);
    uint r = (u + 0x7FFFu + ((u >> 16) & 1u)) >> 16;   // RNE
    return (ushort)r;
}

// async global->LDS, 16B per lane; LDS dest is wave-uniform base + lane*16
__device__ __forceinline__ void gl16(const ushort* g, ushort* l) {
    __builtin_amdgcn_global_load_lds(
        (const __attribute__((address_space(1))) void*)g,
        (__attribute__((address_space(3))) void*)l,
        16, 0, 0);
}

// ---------------- kernel 1: NCHW f32 -> padded NHWC bf16 + pooling partials ----------
__global__ __launch_bounds__(256) void transpose_kernel(const float* __restrict__ x,
                                                        ushort* __restrict__ xT,
                                                        float* __restrict__ part) {
    __shared__ ushort tl[64][264];   // [w][c], pad 8 -> row stride 528B
    const int h = blockIdx.x, b = blockIdx.y;
    const int c = threadIdx.x;
    const float* src = x + (((size_t)(b * C_ + c)) * 64 + h) * 64;   // x[b][c][h][*]
    float s = 0.0f;
    #pragma unroll
    for (int j = 0; j < 16; ++j) {
        float4 v = ((const float4*)src)[j];
        s += v.x + v.y + v.z + v.w;
        tl[j * 4 + 0][c] = f2bf(v.x);
        tl[j * 4 + 1][c] = f2bf(v.y);
        tl[j * 4 + 2][c] = f2bf(v.z);
        tl[j * 4 + 3][c] = f2bf(v.w);
    }
    part[(b * C_ + c) * 64 + h] = s;
    __syncthreads();
    const int cw = threadIdx.x & 31, rw = threadIdx.x >> 5;
    ushort* dstrow = xT + (((size_t)(b * HP_) + h + 1) * HP_ + 1) * C_;  // xT[b][h+1][1][0]
    #pragma unroll
    for (int j = 0; j < 8; ++j) {
        int w = rw + 8 * j;
        *(u16x8*)(dstrow + (size_t)w * C_ + cw * 8) = *(const u16x8*)&tl[w][cw * 8];
    }
}

// ---------------- kernel 1b: zero the spatial halo of xT ----------------
__global__ __launch_bounds__(256) void halo_kernel(ushort* __restrict__ xT) {
    const int b = blockIdx.x, q = blockIdx.y, c = threadIdx.x;
    #pragma unroll
    for (int t = 0; t < 20; ++t) {
        int i = q * 20 + t;
        if (i >= 260) break;
        int hp, wp;
        if (i < 66)       { hp = 0;       wp = i;       }
        else if (i < 132) { hp = 65;      wp = i - 66;  }
        else if (i < 196) { hp = i - 131; wp = 0;       }
        else              { hp = i - 195; wp = 65;      }
        xT[(((size_t)b * HP_ + hp) * HP_ + wp) * C_ + c] = 0;
    }
}

// ---------------- kernel 2: pooled reduce + gating softmax ----------------
__global__ __launch_bounds__(256) void gate_kernel(const float* __restrict__ part,
                                                   const float* __restrict__ gw,
                                                   float* __restrict__ gates) {
    const int b = blockIdx.x, c = threadIdx.x;
    const float4* pp = (const float4*)(part + (size_t)(b * C_ + c) * 64);
    float p = 0.0f;
    #pragma unroll
    for (int j = 0; j < 16; ++j) { float4 v = pp[j]; p += v.x + v.y + v.z + v.w; }
    p *= (1.0f / 4096.0f);
    float l0 = p * gw[0 * C_ + c], l1 = p * gw[1 * C_ + c];
    float l2 = p * gw[2 * C_ + c], l3 = p * gw[3 * C_ + c];
    #pragma unroll
    for (int off = 32; off; off >>= 1) {
        l0 += __shfl_down(l0, off); l1 += __shfl_down(l1, off);
        l2 += __shfl_down(l2, off); l3 += __shfl_down(l3, off);
    }
    __shared__ float red[4][4];
    const int wid = c >> 6, lane = c & 63;
    if (lane == 0) { red[wid][0] = l0; red[wid][1] = l1; red[wid][2] = l2; red[wid][3] = l3; }
    __syncthreads();
    if (c < 4) {
        float logit = red[0][c] + red[1][c] + red[2][c] + red[3][c];
        float m = logit;
        m = fmaxf(m, __shfl_xor(m, 1)); m = fmaxf(m, __shfl_xor(m, 2));
        float ex = expf(logit - m);
        float ssum = ex; ssum += __shfl_xor(ssum, 1); ssum += __shfl_xor(ssum, 2);
        gates[b * 4 + c] = ex / ssum;
    }
}

// ---------------- kernel 3: combine expert weights (tap-major k) ----------------
__global__ __launch_bounds__(256) void combine_kernel(const float* __restrict__ We,
                                                      const float* __restrict__ gates,
                                                      ushort* __restrict__ Wc) {
    const int o = blockIdx.x, c = threadIdx.x;
    __shared__ float g[64];
    if (c < 64) g[c] = gates[c];
    __syncthreads();
    float w[4][9];
    #pragma unroll
    for (int e = 0; e < 4; ++e) {
        const float* p = We + (((size_t)e * O_ + o) * C_ + c) * 9;
        #pragma unroll
        for (int tap = 0; tap < 9; ++tap) w[e][tap] = p[tap];
    }
    #pragma unroll
    for (int b = 0; b < B_; ++b) {
        float g0 = g[b*4+0], g1 = g[b*4+1], g2 = g[b*4+2], g3 = g[b*4+3];
        #pragma unroll
        for (int tap = 0; tap < 9; ++tap) {
            float v = g0*w[0][tap] + g1*w[1][tap] + g2*w[2][tap] + g3*w[3][tap];
            Wc[((size_t)(b * O_ + o)) * KK_ + tap * C_ + c] = f2bf(v);
        }
    }
}

// ---------------- kernel 4: 256x256-tile implicit-GEMM conv, phase-split schedule ----
// grid = 256 blocks (16 n-tiles x 16 samples) = 1/CU, 512 threads (8 waves, 2M x 4N).
// BK=32 tap-uniform tiles, 3-slot LDS ring (96KB), depth-2 prefetch, counted vmcnt(4).
// Per tile: 2 phases {ds_read frags | stage 2 gl16(t+2) -> barrier -> lgkmcnt(0) ->
// setprio(1) 16 MFMA setprio(0) -> barrier}. bF read in phase 0, reused in phase 1.
__global__ __launch_bounds__(512, 2) void conv_kernel(const ushort* __restrict__ xT,
                                                      const ushort* __restrict__ Wc,
                                                      float* __restrict__ out) {
    __shared__ ushort As[3][256][32];   // [slot][o][k]   64B rows, linear DMA dest
    __shared__ ushort Bs[3][256][32];   // [slot][px][k]

    // bijective XCD chunk swizzle: dispatch d -> wgid; 32 consecutive wgids per XCD
    const int d = blockIdx.x;
    const int wgid = (d & 7) * 32 + (d >> 3);
    const int b  = wgid >> 4;
    const int n0 = (wgid & 15) * 256;

    const int tid = threadIdx.x;
    const int wid = tid >> 6, lane = tid & 63;
    const int lr = lane & 15, lg = lane >> 4;
    const int wro = (wid >> 2) * 128;           // wave M-offset (o)
    const int wco = (wid & 3) * 64;             // wave N-offset (px)
    const int rsw = (lg ^ ((lr >> 1) & 3)) * 8; // read-side swizzled granule col (elems)

    // staging roles: each wave DMAs rows [32*wid, 32*wid+32) of A and B per tile
    const int srow = lane >> 2;                 // 0..15
    const int scol = ((lane & 3) ^ ((lane >> 3) & 3)) * 8;   // source-side swizzle
    const ushort* aptr = Wc + ((size_t)(b * O_ + wid * 32 + srow)) * KK_ + scol;
    const ushort* xb = xT + (size_t)b * HP_ * HP_ * C_;
    const int pix0 = n0 + wid * 32 + srow;
    const int pix1 = pix0 + 16;
    const ushort* bp0 = xb + ((size_t)(((pix0 >> 6) + 1) * HP_ + (pix0 & 63) + 1)) * C_ + scol;
    const ushort* bp1 = xb + ((size_t)(((pix1 >> 6) + 1) * HP_ + (pix1 & 63) + 1)) * C_ + scol;

    f32x4 acc[8][4];
    #pragma unroll
    for (int i = 0; i < 8; ++i)
        #pragma unroll
        for (int j = 0; j < 4; ++j) acc[i][j] = (f32x4){0.f, 0.f, 0.f, 0.f};

    auto stageA = [&](int ss, int t) {
        gl16(aptr + t * 32,                    &As[ss][wid * 32][0]);
        gl16(aptr + (size_t)16 * KK_ + t * 32, &As[ss][wid * 32 + 16][0]);
    };
    auto stageB = [&](int ss, int t) {
        const int tap = t >> 3, t3 = (tap * 11) >> 5;   // tap/3
        const int toff = ((t3 - 1) * HP_ + (tap - 3 * t3 - 1)) * C_ + (t & 7) * 32;
        gl16(bp0 + toff, &Bs[ss][wid * 32][0]);
        gl16(bp1 + toff, &Bs[ss][wid * 32 + 16][0]);
    };

    bf16x8 aLo[4], aHi[4], bF[4];

    auto phase0 = [&](int slot, int ss, int t, bool st) {
        #pragma unroll
        for (int m = 0; m < 4; ++m)
            aLo[m] = *(const bf16x8*)&As[slot][wro + m * 16 + lr][rsw];
        #pragma unroll
        for (int n = 0; n < 4; ++n)
            bF[n] = *(const bf16x8*)&Bs[slot][wco + n * 16 + lr][rsw];
        if (st) stageA(ss, t);
        __builtin_amdgcn_s_barrier();
        asm volatile("s_waitcnt lgkmcnt(0)" ::: "memory");
        __builtin_amdgcn_sched_barrier(0);
        __builtin_amdgcn_s_setprio(1);
        #pragma unroll
        for (int m = 0; m < 4; ++m)
            #pragma unroll
            for (int n = 0; n < 4; ++n)
                acc[m][n] = __builtin_amdgcn_mfma_f32_16x16x32_bf16(aLo[m], bF[n], acc[m][n], 0, 0, 0);
        __builtin_amdgcn_s_setprio(0);
        __builtin_amdgcn_s_barrier();
    };
    auto phase1 = [&](int slot, int ss, int t, bool st) {
        #pragma unroll
        for (int m = 0; m < 4; ++m)
            aHi[m] = *(const bf16x8*)&As[slot][wro + 64 + m * 16 + lr][rsw];
        if (st) stageB(ss, t);
        __builtin_amdgcn_s_barrier();
        asm volatile("s_waitcnt lgkmcnt(0)" ::: "memory");
        __builtin_amdgcn_sched_barrier(0);
        __builtin_amdgcn_s_setprio(1);
        #pragma unroll
        for (int m = 0; m < 4; ++m)
            #pragma unroll
            for (int n = 0; n < 4; ++n)
                acc[m + 4][n] = __builtin_amdgcn_mfma_f32_16x16x32_bf16(aHi[m], bF[n], acc[m + 4][n], 0, 0, 0);
        __builtin_amdgcn_s_setprio(0);
        // trailing sync handled at tile boundary (vmcnt + barrier)
    };

    // prologue: stage tiles 0 and 1 fully (order: t0 A,B then t1 A,B)
    stageA(0, 0); stageB(0, 0);
    stageA(1, 1); stageB(1, 1);
    asm volatile("s_waitcnt vmcnt(4)" ::: "memory");   // tile 0 landed, tile 1 in flight
    __builtin_amdgcn_s_barrier();

    #pragma unroll 1
    for (int t = 0; t < 69; t += 3) {
        phase0(0, 2, t + 2, true); phase1(0, 2, t + 2, true);
        asm volatile("s_waitcnt vmcnt(4)" ::: "memory");
        __builtin_amdgcn_s_barrier();
        phase0(1, 0, t + 3, true); phase1(1, 0, t + 3, true);
        asm volatile("s_waitcnt vmcnt(4)" ::: "memory");
        __builtin_amdgcn_s_barrier();
        phase0(2, 1, t + 4, true); phase1(2, 1, t + 4, true);
        asm volatile("s_waitcnt vmcnt(4)" ::: "memory");
        __builtin_amdgcn_s_barrier();
    }
    // tile 69 (slot 0): stage tile 71 into slot 2
    phase0(0, 2, 71, true); phase1(0, 2, 71, true);
    asm volatile("s_waitcnt vmcnt(4)" ::: "memory");
    __builtin_amdgcn_s_barrier();
    // tile 70 (slot 1): no staging; must fully drain (only tile 71's 4 loads in flight)
    phase0(1, 0, 0, false); phase1(1, 0, 0, false);
    asm volatile("s_waitcnt vmcnt(0)" ::: "memory");
    __builtin_amdgcn_s_barrier();
    // tile 71 (slot 2)
    phase0(2, 0, 0, false); phase1(2, 0, 0, false);

    // epilogue: C/D layout col=lane&15, row=(lane>>4)*4+j
    #pragma unroll
    for (int m = 0; m < 8; ++m)
        #pragma unroll
        for (int n = 0; n < 4; ++n)
            #pragma unroll
            for (int j = 0; j < 4; ++j) {
                int ro = wro + m * 16 + lg * 4 + j;
                int co = n0 + wco + n * 16 + lr;
                out[((size_t)(b * O_ + ro)) * HW_ + co] = acc[m][n][j];
            }
}

extern "C" void kernel_launch(void* const* d_in, const int* in_sizes, int n_in,
                              void* d_out, int out_size, void* d_ws, size_t ws_size,
                              hipStream_t stream) {
    const float* x  = (const float*)d_in[0];
    const float* We = (const float*)d_in[1];
    const float* gw = (const float*)d_in[2];
    float* out = (float*)d_out;

    // ws: part @0 (256KB), gates @262144, Wc @263168 (18.87MB -> 19137536),
    //     xT @19137536 (16*66*66*256*2B = 35.68MB) -> ~54.8MB total
    float*  part  = (float*)d_ws;
    float*  gates = (float*)((char*)d_ws + 262144);
    ushort* Wcomb = (ushort*)((char*)d_ws + 263168);
    ushort* xTp   = (ushort*)((char*)d_ws + 19137536);

    transpose_kernel<<<dim3(64, 16), 256, 0, stream>>>(x, xTp, part);
    halo_kernel<<<dim3(16, 13), 256, 0, stream>>>(xTp);
    gate_kernel<<<16, 256, 0, stream>>>(part, gw, gates);
    combine_kernel<<<O_, 256, 0, stream>>>(We, gates, Wcomb);
    conv_kernel<<<256, 512, 0, stream>>>(xTp, Wcomb, out);
}

// Round 6
// 124.710 us; speedup vs baseline: 1.5536x; 1.0058x over previous
//
#include <hip/hip_runtime.h>
#include <hip/hip_bf16.h>

typedef unsigned int uint;
typedef unsigned short ushort;
typedef short bf16x8 __attribute__((ext_vector_type(8)));
typedef ushort u16x8 __attribute__((ext_vector_type(8)));
typedef float f32x4 __attribute__((ext_vector_type(4)));

#define B_ 16
#define C_ 256
#define O_ 256
#define HW_ 4096
#define KK_ 2304   // 9 * 256, tap-major: k = tap*256 + c
#define HP_ 66     // halo-padded spatial dim

__device__ __forceinline__ ushort f2bf(float f) {
    uint u = __builtin_bit_cast(uint, f);
    uint r = (u + 0x7FFFu + ((u >> 16) & 1u)) >> 16;   // RNE
    return (ushort)r;
}

// async global->LDS, 16B per lane; LDS dest is wave-uniform base + lane*16
__device__ __forceinline__ void gl16(const ushort* g, ushort* l) {
    __builtin_amdgcn_global_load_lds(
        (const __attribute__((address_space(1))) void*)g,
        (__attribute__((address_space(3))) void*)l,
        16, 0, 0);
}

// ---------------- kernel 1: NCHW f32 -> padded NHWC bf16 + pool partials + halo ------
__global__ __launch_bounds__(256) void transpose_kernel(const float* __restrict__ x,
                                                        ushort* __restrict__ xT,
                                                        float* __restrict__ part) {
    __shared__ ushort tl[64][264];   // [w][c], pad 8 -> row stride 528B
    const int h = blockIdx.x, b = blockIdx.y;
    const int c = threadIdx.x;
    const float* src = x + (((size_t)(b * C_ + c)) * 64 + h) * 64;   // x[b][c][h][*]
    float s = 0.0f;
    #pragma unroll
    for (int j = 0; j < 16; ++j) {
        float4 v = ((const float4*)src)[j];
        s += v.x + v.y + v.z + v.w;
        tl[j * 4 + 0][c] = f2bf(v.x);
        tl[j * 4 + 1][c] = f2bf(v.y);
        tl[j * 4 + 2][c] = f2bf(v.z);
        tl[j * 4 + 3][c] = f2bf(v.w);
    }
    part[(b * C_ + c) * 64 + h] = s;
    // zero 5 halo pixels per block (260 total per sample, 64 blocks x 5 = 320 >= 260)
    ushort* xbs = xT + (size_t)b * HP_ * HP_ * C_;
    #pragma unroll
    for (int t = 0; t < 5; ++t) {
        int i = h * 5 + t;
        if (i < 260) {
            int hp, wp;
            if (i < 66)       { hp = 0;       wp = i;       }
            else if (i < 132) { hp = 65;      wp = i - 66;  }
            else if (i < 196) { hp = i - 131; wp = 0;       }
            else              { hp = i - 195; wp = 65;      }
            xbs[((size_t)hp * HP_ + wp) * C_ + c] = 0;
        }
    }
    __syncthreads();
    const int cw = threadIdx.x & 31, rw = threadIdx.x >> 5;
    ushort* dstrow = xT + (((size_t)(b * HP_) + h + 1) * HP_ + 1) * C_;  // xT[b][h+1][1][0]
    #pragma unroll
    for (int j = 0; j < 8; ++j) {
        int w = rw + 8 * j;
        *(u16x8*)(dstrow + (size_t)w * C_ + cw * 8) = *(const u16x8*)&tl[w][cw * 8];
    }
}

// ---------------- kernel 2: pooled reduce + gating softmax ----------------
__global__ __launch_bounds__(256) void gate_kernel(const float* __restrict__ part,
                                                   const float* __restrict__ gw,
                                                   float* __restrict__ gates) {
    const int b = blockIdx.x, c = threadIdx.x;
    const float4* pp = (const float4*)(part + (size_t)(b * C_ + c) * 64);
    float p = 0.0f;
    #pragma unroll
    for (int j = 0; j < 16; ++j) { float4 v = pp[j]; p += v.x + v.y + v.z + v.w; }
    p *= (1.0f / 4096.0f);
    float l0 = p * gw[0 * C_ + c], l1 = p * gw[1 * C_ + c];
    float l2 = p * gw[2 * C_ + c], l3 = p * gw[3 * C_ + c];
    #pragma unroll
    for (int off = 32; off; off >>= 1) {
        l0 += __shfl_down(l0, off); l1 += __shfl_down(l1, off);
        l2 += __shfl_down(l2, off); l3 += __shfl_down(l3, off);
    }
    __shared__ float red[4][4];
    const int wid = c >> 6, lane = c & 63;
    if (lane == 0) { red[wid][0] = l0; red[wid][1] = l1; red[wid][2] = l2; red[wid][3] = l3; }
    __syncthreads();
    if (c < 4) {
        float logit = red[0][c] + red[1][c] + red[2][c] + red[3][c];
        float m = logit;
        m = fmaxf(m, __shfl_xor(m, 1)); m = fmaxf(m, __shfl_xor(m, 2));
        float ex = expf(logit - m);
        float ssum = ex; ssum += __shfl_xor(ssum, 1); ssum += __shfl_xor(ssum, 2);
        gates[b * 4 + c] = ex / ssum;
    }
}

// ---------------- kernel 3: combine expert weights (tap-major k) ----------------
__global__ __launch_bounds__(256) void combine_kernel(const float* __restrict__ We,
                                                      const float* __restrict__ gates,
                                                      ushort* __restrict__ Wc) {
    const int o = blockIdx.x, c = threadIdx.x;
    __shared__ float g[64];
    if (c < 64) g[c] = gates[c];
    __syncthreads();
    float w[4][9];
    #pragma unroll
    for (int e = 0; e < 4; ++e) {
        const float* p = We + (((size_t)e * O_ + o) * C_ + c) * 9;
        #pragma unroll
        for (int tap = 0; tap < 9; ++tap) w[e][tap] = p[tap];
    }
    #pragma unroll
    for (int b = 0; b < B_; ++b) {
        float g0 = g[b*4+0], g1 = g[b*4+1], g2 = g[b*4+2], g3 = g[b*4+3];
        #pragma unroll
        for (int tap = 0; tap < 9; ++tap) {
            float v = g0*w[0][tap] + g1*w[1][tap] + g2*w[2][tap] + g3*w[3][tap];
            Wc[((size_t)(b * O_ + o)) * KK_ + tap * C_ + c] = f2bf(v);
        }
    }
}

// ---------------- kernel 4: 256x256 implicit-GEMM conv, read-ahead pipeline ----------
// grid = 256 blocks (16 n-tiles x 16 samples) = 1/CU, 512 threads (8 waves, 2M x 4N).
// BK=32 tap-uniform tiles, 3-slot LDS ring (96KB), depth-2 DMA prefetch, vmcnt(4).
// Fragment ds_reads are pipelined ONE PHASE AHEAD so LDS service overlaps MFMA:
//   phase0: issue aHi reads -> lgkmcnt(4) [waits prev phase's reads] -> MFMA(aLo,bF)
//   mid:    vmcnt(4) + barrier  [all waves' slot(t+1) DMAs landed]
//   phase1: issue next-tile aLo'/bF' reads -> lgkmcnt(8) [waits aHi] -> MFMA(aHi,bF)
//   end:    barrier  [all slot-t reads drained -> slot-t restageable]
__global__ __launch_bounds__(512, 2) void conv_kernel(const ushort* __restrict__ xT,
                                                      const ushort* __restrict__ Wc,
                                                      float* __restrict__ out) {
    __shared__ ushort As[3][256][32];   // [slot][o][k]   64B rows, linear DMA dest
    __shared__ ushort Bs[3][256][32];   // [slot][px][k]

    // bijective XCD chunk swizzle: 32 consecutive wgids per XCD
    const int d = blockIdx.x;
    const int wgid = (d & 7) * 32 + (d >> 3);
    const int b  = wgid >> 4;
    const int n0 = (wgid & 15) * 256;

    const int tid = threadIdx.x;
    const int wid = tid >> 6, lane = tid & 63;
    const int lr = lane & 15, lg = lane >> 4;
    const int wro = (wid >> 2) * 128;           // wave M-offset (o)
    const int wco = (wid & 3) * 64;             // wave N-offset (px)
    const int rsw = (lg ^ ((lr >> 1) & 3)) * 8; // read-side swizzled granule col (elems)

    // staging roles: each wave DMAs rows [32*wid, 32*wid+32) of A and B per tile
    const int srow = lane >> 2;                 // 0..15
    const int scol = ((lane & 3) ^ ((lane >> 3) & 3)) * 8;   // source-side swizzle
    const ushort* aptr = Wc + ((size_t)(b * O_ + wid * 32 + srow)) * KK_ + scol;
    const ushort* xb = xT + (size_t)b * HP_ * HP_ * C_;
    const int pix0 = n0 + wid * 32 + srow;
    const int pix1 = pix0 + 16;
    const ushort* bp0 = xb + ((size_t)(((pix0 >> 6) + 1) * HP_ + (pix0 & 63) + 1)) * C_ + scol;
    const ushort* bp1 = xb + ((size_t)(((pix1 >> 6) + 1) * HP_ + (pix1 & 63) + 1)) * C_ + scol;

    f32x4 acc[8][4];
    #pragma unroll
    for (int i = 0; i < 8; ++i)
        #pragma unroll
        for (int j = 0; j < 4; ++j) acc[i][j] = (f32x4){0.f, 0.f, 0.f, 0.f};

    auto stageA = [&](int ss, int t) {
        gl16(aptr + t * 32,                    &As[ss][wid * 32][0]);
        gl16(aptr + (size_t)16 * KK_ + t * 32, &As[ss][wid * 32 + 16][0]);
    };
    auto stageB = [&](int ss, int t) {
        const int tap = t >> 3, t3 = (tap * 11) >> 5;   // tap/3
        const int toff = ((t3 - 1) * HP_ + (tap - 3 * t3 - 1)) * C_ + (t & 7) * 32;
        gl16(bp0 + toff, &Bs[ss][wid * 32][0]);
        gl16(bp1 + toff, &Bs[ss][wid * 32 + 16][0]);
    };

    bf16x8 aLo[4], aHi[4], bF0[4], bF1[4];

    auto dsA = [&](int slot, int roff, bf16x8* dst) {
        #pragma unroll
        for (int m = 0; m < 4; ++m)
            dst[m] = *(const bf16x8*)&As[slot][wro + roff + m * 16 + lr][rsw];
    };
    auto dsB = [&](int slot, bf16x8* dst) {
        #pragma unroll
        for (int n = 0; n < 4; ++n)
            dst[n] = *(const bf16x8*)&Bs[slot][wco + n * 16 + lr][rsw];
    };
    auto mfma16 = [&](int ao, bf16x8* a, bf16x8* bv) {
        #pragma unroll
        for (int m = 0; m < 4; ++m)
            #pragma unroll
            for (int n = 0; n < 4; ++n)
                acc[ao + m][n] = __builtin_amdgcn_mfma_f32_16x16x32_bf16(a[m], bv[n], acc[ao + m][n], 0, 0, 0);
    };

    // mode: 0 steady (stage + read-ahead), 1 penultimate (drain vm, read-ahead), 2 last
    auto tile = [&](int scur, int snxt, int tstg, bf16x8* bUse, bf16x8* bNew, int mode) {
        const int sstg = (scur + 2) % 3;
        if (mode == 0) { stageA(sstg, tstg); stageB(sstg, tstg); }
        dsA(scur, 64, aHi);                                  // phase1 frags (read-ahead)
        asm volatile("s_waitcnt lgkmcnt(4)" ::: "memory");   // aLo/bUse ready
        __builtin_amdgcn_sched_barrier(0);
        __builtin_amdgcn_s_setprio(1);
        mfma16(0, aLo, bUse);
        __builtin_amdgcn_s_setprio(0);
        __builtin_amdgcn_sched_barrier(0);
        if (mode == 0) asm volatile("s_waitcnt vmcnt(4)" ::: "memory");
        if (mode == 1) asm volatile("s_waitcnt vmcnt(0)" ::: "memory");
        if (mode != 2) {
            __builtin_amdgcn_s_barrier();                    // slot snxt DMA-complete, all waves
            dsA(snxt, 0, aLo);                               // next-tile frags (read-ahead)
            dsB(snxt, bNew);
            asm volatile("s_waitcnt lgkmcnt(8)" ::: "memory");  // aHi ready
        } else {
            asm volatile("s_waitcnt lgkmcnt(0)" ::: "memory");
        }
        __builtin_amdgcn_sched_barrier(0);
        __builtin_amdgcn_s_setprio(1);
        mfma16(4, aHi, bUse);
        __builtin_amdgcn_s_setprio(0);
        __builtin_amdgcn_sched_barrier(0);
        if (mode != 2) __builtin_amdgcn_s_barrier();         // slot scur reads drained
    };

    // prologue: stage tiles 0,1; wait tile 0; preload its frags
    stageA(0, 0); stageB(0, 0);
    stageA(1, 1); stageB(1, 1);
    asm volatile("s_waitcnt vmcnt(4)" ::: "memory");
    __builtin_amdgcn_s_barrier();
    dsA(0, 0, aLo);
    dsB(0, bF0);

    // 6-tile unrolled body: slot period 3 x bF ping-pong period 2
    #pragma unroll 1
    for (int t = 0; t < 66; t += 6) {
        tile(0, 1, t + 2, bF0, bF1, 0);
        tile(1, 2, t + 3, bF1, bF0, 0);
        tile(2, 0, t + 4, bF0, bF1, 0);
        tile(0, 1, t + 5, bF1, bF0, 0);
        tile(1, 2, t + 6, bF0, bF1, 0);
        tile(2, 0, t + 7, bF1, bF0, 0);
    }
    tile(0, 1, 68, bF0, bF1, 0);
    tile(1, 2, 69, bF1, bF0, 0);
    tile(2, 0, 70, bF0, bF1, 0);
    tile(0, 1, 71, bF1, bF0, 0);
    tile(1, 2, 0,  bF0, bF1, 1);   // tile 70: drain vm, read-ahead slot 2
    tile(2, 0, 0,  bF1, bF0, 2);   // tile 71: final

    // epilogue: C/D layout col=lane&15, row=(lane>>4)*4+j
    #pragma unroll
    for (int m = 0; m < 8; ++m)
        #pragma unroll
        for (int n = 0; n < 4; ++n)
            #pragma unroll
            for (int j = 0; j < 4; ++j) {
                int ro = wro + m * 16 + lg * 4 + j;
                int co = n0 + wco + n * 16 + lr;
                out[((size_t)(b * O_ + ro)) * HW_ + co] = acc[m][n][j];
            }
}

extern "C" void kernel_launch(void* const* d_in, const int* in_sizes, int n_in,
                              void* d_out, int out_size, void* d_ws, size_t ws_size,
                              hipStream_t stream) {
    const float* x  = (const float*)d_in[0];
    const float* We = (const float*)d_in[1];
    const float* gw = (const float*)d_in[2];
    float* out = (float*)d_out;

    // ws: part @0 (256KB), gates @262144, Wc @263168 (18.87MB -> 19137536),
    //     xT @19137536 (16*66*66*256*2B = 35.68MB) -> ~54.8MB total
    float*  part  = (float*)d_ws;
    float*  gates = (float*)((char*)d_ws + 262144);
    ushort* Wcomb = (ushort*)((char*)d_ws + 263168);
    ushort* xTp   = (ushort*)((char*)d_ws + 19137536);

    transpose_kernel<<<dim3(64, 16), 256, 0, stream>>>(x, xTp, part);
    gate_kernel<<<16, 256, 0, stream>>>(part, gw, gates);
    combine_kernel<<<O_, 256, 0, stream>>>(We, gates, Wcomb);
    conv_kernel<<<256, 512, 0, stream>>>(xTp, Wcomb, out);
}

// Round 7
// 113.499 us; speedup vs baseline: 1.7071x; 1.0988x over previous
//
#include <hip/hip_runtime.h>
#include <hip/hip_bf16.h>

typedef unsigned int uint;
typedef unsigned short ushort;
typedef short bf16x8 __attribute__((ext_vector_type(8)));
typedef ushort u16x8 __attribute__((ext_vector_type(8)));
typedef float f32x4 __attribute__((ext_vector_type(4)));

#define B_ 16
#define C_ 256
#define O_ 256
#define HW_ 4096
#define KK_ 2304   // 9 * 256, tap-major: k = tap*256 + c
#define HP_ 66     // halo-padded spatial dim

__device__ __forceinline__ ushort f2bf(float f) {
    uint u = __builtin_bit_cast(uint, f);
    uint r = (u + 0x7FFFu + ((u >> 16) & 1u)) >> 16;   // RNE
    return (ushort)r;
}

// async global->LDS, 16B per lane; LDS dest is wave-uniform base + lane*16
__device__ __forceinline__ void gl16(const ushort* g, ushort* l) {
    __builtin_amdgcn_global_load_lds(
        (const __attribute__((address_space(1))) void*)g,
        (__attribute__((address_space(3))) void*)l,
        16, 0, 0);
}

// ---------------- kernel 1: NCHW f32 -> padded NHWC bf16 + pool partials + halo ------
__global__ __launch_bounds__(256) void transpose_kernel(const float* __restrict__ x,
                                                        ushort* __restrict__ xT,
                                                        float* __restrict__ part) {
    __shared__ ushort tl[64][264];   // [w][c], pad 8 -> row stride 528B
    const int h = blockIdx.x, b = blockIdx.y;
    const int c = threadIdx.x;
    const float* src = x + (((size_t)(b * C_ + c)) * 64 + h) * 64;   // x[b][c][h][*]
    float s = 0.0f;
    #pragma unroll
    for (int j = 0; j < 16; ++j) {
        float4 v = ((const float4*)src)[j];
        s += v.x + v.y + v.z + v.w;
        tl[j * 4 + 0][c] = f2bf(v.x);
        tl[j * 4 + 1][c] = f2bf(v.y);
        tl[j * 4 + 2][c] = f2bf(v.z);
        tl[j * 4 + 3][c] = f2bf(v.w);
    }
    part[(b * C_ + c) * 64 + h] = s;
    // zero 5 halo pixels per block (260 total per sample, 64 blocks x 5 = 320 >= 260)
    ushort* xbs = xT + (size_t)b * HP_ * HP_ * C_;
    #pragma unroll
    for (int t = 0; t < 5; ++t) {
        int i = h * 5 + t;
        if (i < 260) {
            int hp, wp;
            if (i < 66)       { hp = 0;       wp = i;       }
            else if (i < 132) { hp = 65;      wp = i - 66;  }
            else if (i < 196) { hp = i - 131; wp = 0;       }
            else              { hp = i - 195; wp = 65;      }
            xbs[((size_t)hp * HP_ + wp) * C_ + c] = 0;
        }
    }
    __syncthreads();
    const int cw = threadIdx.x & 31, rw = threadIdx.x >> 5;
    ushort* dstrow = xT + (((size_t)(b * HP_) + h + 1) * HP_ + 1) * C_;  // xT[b][h+1][1][0]
    #pragma unroll
    for (int j = 0; j < 8; ++j) {
        int w = rw + 8 * j;
        *(u16x8*)(dstrow + (size_t)w * C_ + cw * 8) = *(const u16x8*)&tl[w][cw * 8];
    }
}

// ---------------- kernel 2: pooled reduce + gating softmax ----------------
__global__ __launch_bounds__(256) void gate_kernel(const float* __restrict__ part,
                                                   const float* __restrict__ gw,
                                                   float* __restrict__ gates) {
    const int b = blockIdx.x, c = threadIdx.x;
    const float4* pp = (const float4*)(part + (size_t)(b * C_ + c) * 64);
    float p = 0.0f;
    #pragma unroll
    for (int j = 0; j < 16; ++j) { float4 v = pp[j]; p += v.x + v.y + v.z + v.w; }
    p *= (1.0f / 4096.0f);
    float l0 = p * gw[0 * C_ + c], l1 = p * gw[1 * C_ + c];
    float l2 = p * gw[2 * C_ + c], l3 = p * gw[3 * C_ + c];
    #pragma unroll
    for (int off = 32; off; off >>= 1) {
        l0 += __shfl_down(l0, off); l1 += __shfl_down(l1, off);
        l2 += __shfl_down(l2, off); l3 += __shfl_down(l3, off);
    }
    __shared__ float red[4][4];
    const int wid = c >> 6, lane = c & 63;
    if (lane == 0) { red[wid][0] = l0; red[wid][1] = l1; red[wid][2] = l2; red[wid][3] = l3; }
    __syncthreads();
    if (c < 4) {
        float logit = red[0][c] + red[1][c] + red[2][c] + red[3][c];
        float m = logit;
        m = fmaxf(m, __shfl_xor(m, 1)); m = fmaxf(m, __shfl_xor(m, 2));
        float ex = expf(logit - m);
        float ssum = ex; ssum += __shfl_xor(ssum, 1); ssum += __shfl_xor(ssum, 2);
        gates[b * 4 + c] = ex / ssum;
    }
}

// ---------------- kernel 3: combine expert weights (tap-major k) ----------------
__global__ __launch_bounds__(256) void combine_kernel(const float* __restrict__ We,
                                                      const float* __restrict__ gates,
                                                      ushort* __restrict__ Wc) {
    const int o = blockIdx.x, c = threadIdx.x;
    __shared__ float g[64];
    if (c < 64) g[c] = gates[c];
    __syncthreads();
    float w[4][9];
    #pragma unroll
    for (int e = 0; e < 4; ++e) {
        const float* p = We + (((size_t)e * O_ + o) * C_ + c) * 9;
        #pragma unroll
        for (int tap = 0; tap < 9; ++tap) w[e][tap] = p[tap];
    }
    #pragma unroll
    for (int b = 0; b < B_; ++b) {
        float g0 = g[b*4+0], g1 = g[b*4+1], g2 = g[b*4+2], g3 = g[b*4+3];
        #pragma unroll
        for (int tap = 0; tap < 9; ++tap) {
            float v = g0*w[0][tap] + g1*w[1][tap] + g2*w[2][tap] + g3*w[3][tap];
            Wc[((size_t)(b * O_ + o)) * KK_ + tap * C_ + c] = f2bf(v);
        }
    }
}

// ---------------- kernel 4: 256x256 implicit-GEMM conv, BK=64, 1-barrier tiles ------
// grid = 256 blocks (16 n-tiles x 16 samples) = 1/CU, 512 threads (8 waves, 2M x 4N).
// BK=64 (4 tiles per tap, 36 tiles), 2-slot LDS (128KB). Per tile: one barrier, one
// vmcnt(0) (drains gl16s issued ~2000cyc earlier), and 4 lgkm-staggered MFMA phases
// with frag reads pipelined one phase ahead. Granule XOR swizzle (g ^= row&7) applied
// on the per-lane gl16 SOURCE address and on the ds_read column -> 2 lanes/bank.
__global__ __launch_bounds__(512, 2) void conv_kernel(const ushort* __restrict__ xT,
                                                      const ushort* __restrict__ Wc,
                                                      float* __restrict__ out) {
    __shared__ ushort As[2][256][64];   // [slot][o][k]   128B rows, linear DMA dest
    __shared__ ushort Bs[2][256][64];   // [slot][px][k]

    // bijective XCD chunk swizzle: 32 consecutive wgids per XCD (2 samples/XCD)
    const int d = blockIdx.x;
    const int wgid = (d & 7) * 32 + (d >> 3);
    const int b  = wgid >> 4;
    const int n0 = (wgid & 15) * 256;

    const int tid = threadIdx.x;
    const int wid = tid >> 6, lane = tid & 63;
    const int lr = lane & 15, lg = lane >> 4;
    const int wro = (wid >> 2) * 128;           // wave M-offset (o)
    const int wco = (wid & 3) * 64;             // wave N-offset (px)

    // staging roles: wave stages rows [32*wid, 32*wid+32) of A and B (4 gl16 each)
    const int srow = lane >> 3;                 // 0..7 row within 8-row chunk
    const int sgr  = (lane & 7) ^ srow;         // source granule (XOR swizzle)
    const ushort* aS = Wc + ((size_t)(b * O_ + wid * 32 + srow)) * KK_ + sgr * 8;
    const ushort* xb = xT + (size_t)b * HP_ * HP_ * C_;
    const ushort* bS[4];
    #pragma unroll
    for (int i = 0; i < 4; ++i) {
        int p = n0 + wid * 32 + i * 8 + srow;
        bS[i] = xb + ((size_t)(((p >> 6) + 1) * HP_ + (p & 63) + 1)) * C_ + sgr * 8;
    }

    f32x4 acc[8][4];
    #pragma unroll
    for (int i = 0; i < 8; ++i)
        #pragma unroll
        for (int j = 0; j < 4; ++j) acc[i][j] = (f32x4){0.f, 0.f, 0.f, 0.f};

    auto stage = [&](int ss, int t) {
        const int tap = t >> 2, c0 = (t & 3) * 64;
        const int t3 = (tap * 11) >> 5;          // tap/3
        const int toff = ((t3 - 1) * HP_ + (tap - 3 * t3 - 1)) * C_ + c0;
        #pragma unroll
        for (int i = 0; i < 4; ++i)
            gl16(aS + (size_t)t * 64 + i * 8 * KK_, &As[ss][wid * 32 + i * 8][0]);
        #pragma unroll
        for (int i = 0; i < 4; ++i)
            gl16(bS[i] + toff, &Bs[ss][wid * 32 + i * 8][0]);
    };

    bf16x8 aLo[4], aHi[4], bFA[4], bFB[4];

    auto dsA = [&](int s, int half, int ksub, bf16x8* dst) {
        #pragma unroll
        for (int m = 0; m < 4; ++m)
            dst[m] = *(const bf16x8*)
                &As[s][wro + half * 64 + m * 16 + lr][(((ksub << 2) | lg) ^ (lr & 7)) * 8];
    };
    auto dsB = [&](int s, int ksub, bf16x8* dst) {
        #pragma unroll
        for (int n = 0; n < 4; ++n)
            dst[n] = *(const bf16x8*)
                &Bs[s][wco + n * 16 + lr][(((ksub << 2) | lg) ^ (lr & 7)) * 8];
    };
    auto mfma16 = [&](int ao, bf16x8* a, bf16x8* bv) {
        #pragma unroll
        for (int m = 0; m < 4; ++m)
            #pragma unroll
            for (int n = 0; n < 4; ++n)
                acc[ao + m][n] = __builtin_amdgcn_mfma_f32_16x16x32_bf16(a[m], bv[n], acc[ao + m][n], 0, 0, 0);
    };

    // prologue: stage tile 0 into slot 0, publish, pre-issue first frag batch
    stage(0, 0);
    asm volatile("s_waitcnt vmcnt(0)" ::: "memory");
    __builtin_amdgcn_s_barrier();
    dsB(0, 0, bFA); dsA(0, 0, 0, aLo);            // R0: 8 reads

    #pragma unroll 1
    for (int t = 0; t < 35; ++t) {
        const int s = t & 1;
        stage(s ^ 1, t + 1);                      // 8 gl16 -> other slot (vmcnt only)
        dsA(s, 1, 0, aHi);                        // R1: 4
        asm volatile("s_waitcnt lgkmcnt(4)" ::: "memory");   // R0 done
        __builtin_amdgcn_sched_barrier(0);
        __builtin_amdgcn_s_setprio(1);
        mfma16(0, aLo, bFA);
        __builtin_amdgcn_s_setprio(0);
        dsB(s, 1, bFB); dsA(s, 0, 1, aLo);        // R2: 8
        asm volatile("s_waitcnt lgkmcnt(8)" ::: "memory");   // R1 done
        __builtin_amdgcn_sched_barrier(0);
        __builtin_amdgcn_s_setprio(1);
        mfma16(4, aHi, bFA);
        __builtin_amdgcn_s_setprio(0);
        dsA(s, 1, 1, aHi);                        // R3: 4
        asm volatile("s_waitcnt lgkmcnt(4)" ::: "memory");   // R2 done
        __builtin_amdgcn_sched_barrier(0);
        __builtin_amdgcn_s_setprio(1);
        mfma16(0, aLo, bFB);
        __builtin_amdgcn_s_setprio(0);
        asm volatile("s_waitcnt lgkmcnt(0)" ::: "memory");   // R3 done
        __builtin_amdgcn_sched_barrier(0);
        __builtin_amdgcn_s_setprio(1);
        mfma16(4, aHi, bFB);
        __builtin_amdgcn_s_setprio(0);
        asm volatile("s_waitcnt vmcnt(0)" ::: "memory");     // tile t+1 landed (issued ~2k cyc ago)
        __builtin_amdgcn_s_barrier();
        dsB(s ^ 1, 0, bFA); dsA(s ^ 1, 0, 0, aLo);           // pre-batch for tile t+1
    }
    // final tile t=35 (slot 1), no staging
    {
        const int s = 1;
        dsA(s, 1, 0, aHi);
        asm volatile("s_waitcnt lgkmcnt(4)" ::: "memory");
        __builtin_amdgcn_sched_barrier(0);
        mfma16(0, aLo, bFA);
        dsB(s, 1, bFB); dsA(s, 0, 1, aLo);
        asm volatile("s_waitcnt lgkmcnt(8)" ::: "memory");
        __builtin_amdgcn_sched_barrier(0);
        mfma16(4, aHi, bFA);
        dsA(s, 1, 1, aHi);
        asm volatile("s_waitcnt lgkmcnt(4)" ::: "memory");
        __builtin_amdgcn_sched_barrier(0);
        mfma16(0, aLo, bFB);
        asm volatile("s_waitcnt lgkmcnt(0)" ::: "memory");
        __builtin_amdgcn_sched_barrier(0);
        mfma16(4, aHi, bFB);
    }

    // epilogue: C/D layout col=lane&15, row=(lane>>4)*4+j
    #pragma unroll
    for (int m = 0; m < 8; ++m)
        #pragma unroll
        for (int n = 0; n < 4; ++n)
            #pragma unroll
            for (int j = 0; j < 4; ++j) {
                int ro = wro + m * 16 + lg * 4 + j;
                int co = n0 + wco + n * 16 + lr;
                out[((size_t)(b * O_ + ro)) * HW_ + co] = acc[m][n][j];
            }
}

extern "C" void kernel_launch(void* const* d_in, const int* in_sizes, int n_in,
                              void* d_out, int out_size, void* d_ws, size_t ws_size,
                              hipStream_t stream) {
    const float* x  = (const float*)d_in[0];
    const float* We = (const float*)d_in[1];
    const float* gw = (const float*)d_in[2];
    float* out = (float*)d_out;

    // ws: part @0 (256KB), gates @262144, Wc @263168 (18.87MB -> 19137536),
    //     xT @19137536 (16*66*66*256*2B = 35.68MB) -> ~54.8MB total
    float*  part  = (float*)d_ws;
    float*  gates = (float*)((char*)d_ws + 262144);
    ushort* Wcomb = (ushort*)((char*)d_ws + 263168);
    ushort* xTp   = (ushort*)((char*)d_ws + 19137536);

    transpose_kernel<<<dim3(64, 16), 256, 0, stream>>>(x, xTp, part);
    gate_kernel<<<16, 256, 0, stream>>>(part, gw, gates);
    combine_kernel<<<O_, 256, 0, stream>>>(We, gates, Wcomb);
    conv_kernel<<<256, 512, 0, stream>>>(xTp, Wcomb, out);
}